// Round 10
// baseline (200.819 us; speedup 1.0000x reference)
//
#include <hip/hip_runtime.h>
#include <hip/hip_bf16.h>

// CrossAttention: B=4, C=256, N=4096, OUT=256, temp=16.
// v18: flash reverted to v11 (v17 barrier-halving hurt: 99.5->107.5,
//      MfmaUtil 30.5->26.7 - per-interval barrier HELPS P/C interleave).
//      proj: two targeted fixes, skeleton unchanged:
//  (1) staging via in-lane 4x4 transpose: 16 f32x4 loads/lane (wave instr
//      = 4 rows x 256B = 1KB coalescing sweet spot) vs 64 scalar strided;
//      LDS writes 16x short4 with (k+q)&3 write-order rotation (~4-way,
//      same class as v12). LDS layout unchanged -> MFMA reader untouched.
//  (2) K+V merged into one block (grid z: 0=Q, 1=KV): xx staged ONCE,
//      two sequential MFMA+epilogue passes (register overlay, peak ~130
//      VGPR < 256 cap). 768->512 block-stagings; 512 blocks = exact 2/CU
//      residency. Separate 32KB ob buffer keeps xs intact for pass 2
//      (LDS 65KB -> still 2/CU). Epilogues verbatim from v12.
//      Arithmetic bit-identical: absmax must stay 4.88e-4 exactly.
// Workspace: qg 8.4MB + kt 8.4MB + vt 8.4MB + wb 384KB.

typedef __attribute__((ext_vector_type(8))) short bf16x8;
typedef __attribute__((ext_vector_type(4))) float f32x4;
typedef __attribute__((ext_vector_type(4))) short short4t;

constexpr int B_ = 4;
constexpr int C_ = 256;
constexpr int N_ = 4096;
constexpr int O_ = 256;
constexpr float INV_TEMP = 1.0f / 16.0f;
constexpr int NIT = 64;   // 64-key blocks (all 4096 keys, SPLIT=1)

__device__ __forceinline__ short f2bf(float f) {
  union { float f; unsigned u; } v; v.f = f;
  unsigned r = v.u + 0x7fffu + ((v.u >> 16) & 1u);   // RNE
  return (short)(r >> 16);
}

// ---------------------------------------------------------------------------
__global__ void wcvt(const float* __restrict__ Wq, const float* __restrict__ Wk,
                     const float* __restrict__ Wv, short* __restrict__ wb) {
  int i = blockIdx.x * 256 + threadIdx.x;        // 0..196607
  int mat = i >> 16, off = i & 65535;
  const float* W = (mat == 0) ? Wq : (mat == 1 ? Wk : Wv);
  wb[i] = f2bf(W[off]);
}

// ---------------------------------------------------------------------------
// Projections v18. Grid (64, B, 2). Block 256 (4 waves).
// z=0: Q from x. z=1: K AND V from one xx staging (two MFMA passes).
// LDS: xs 33.8KB (staged tile, intact across passes) + ob 32KB (assembly).
// ---------------------------------------------------------------------------
__global__ __launch_bounds__(256, 2) void qkv_proj(
    const float* __restrict__ x, const float* __restrict__ xx,
    const short* __restrict__ wb,
    short* __restrict__ qg, short* __restrict__ kt, short* __restrict__ vt) {
  const int n0 = blockIdx.x * 64;
  const int b  = blockIdx.y;
  const int kv = blockIdx.z;                     // 0=Q, 1=K+V
  const float* src = kv ? xx : x;
  const int tid = threadIdx.x;
  const int w = tid >> 6, lane = tid & 63;
  const int g = lane >> 4, c16 = lane & 15;

  __shared__ __align__(16) short xs[64][264];    // staged tile (stays live)
  __shared__ __align__(16) short ob[16384];      // out-assembly (32KB)

  {  // staging: in-lane 4x4 transpose. Thread: n-quad q (4 cols), c-group rg
     // (16 rows). 16 f32x4 loads (wave: 4 rows x 256B = 1KB contiguous/instr),
     // then 16 short4 LDS writes, write-order rotated by (k+q)&3 for banks.
    const int q  = tid & 15;
    const int rg = tid >> 4;
    const float* sp = src + (size_t)b * C_ * N_ + n0 + q * 4;
    f32x4 v[16];                                 // 64 VGPR, deep MLP
#pragma unroll
    for (int i = 0; i < 16; ++i)
      v[i] = *(const f32x4*)(sp + (size_t)(rg * 16 + i) * N_);
#pragma unroll
    for (int jj = 0; jj < 4; ++jj)
#pragma unroll
      for (int k = 0; k < 4; ++k) {
        const int i4 = (k + q) & 3;              // bank-rotation (order only)
        short4t s4;
#pragma unroll
        for (int j = 0; j < 4; ++j) s4[j] = f2bf(v[i4 * 4 + j][jj]);
        *(short4t*)&xs[q * 4 + jj][rg * 16 + i4 * 4] = s4;
      }
  }
  __syncthreads();

  const int npass = kv ? 2 : 1;
#pragma unroll 1
  for (int p = 0; p < npass; ++p) {
    const int mat = kv ? (1 + p) : 0;            // 0=Q, 1=K, 2=V
    const short* W = wb + mat * 65536;

    f32x4 acc[4][4];
#pragma unroll
    for (int i = 0; i < 4; ++i)
#pragma unroll
      for (int j = 0; j < 4; ++j) acc[i][j] = (f32x4){0.f, 0.f, 0.f, 0.f};

#pragma unroll
    for (int ko = 0; ko < 8; ++ko) {
      bf16x8 wfr[4], xfr[4];
#pragma unroll
      for (int ot = 0; ot < 4; ++ot)
        wfr[ot] = *(const bf16x8*)&W[(w * 64 + ot * 16 + c16) * C_ +
                                     ko * 32 + g * 8];
#pragma unroll
      for (int nt = 0; nt < 4; ++nt)
        xfr[nt] = *(const bf16x8*)&xs[nt * 16 + c16][ko * 32 + g * 8];
      if (mat < 2) {
#pragma unroll
        for (int ot = 0; ot < 4; ++ot)
#pragma unroll
          for (int nt = 0; nt < 4; ++nt)
            acc[ot][nt] = __builtin_amdgcn_mfma_f32_16x16x32_bf16(
                wfr[ot], xfr[nt], acc[ot][nt], 0, 0, 0);
      } else {  // V: swapped operands -> D rows = m, cols = o
#pragma unroll
        for (int mt = 0; mt < 4; ++mt)
#pragma unroll
          for (int ot = 0; ot < 4; ++ot)
            acc[mt][ot] = __builtin_amdgcn_mfma_f32_16x16x32_bf16(
                xfr[mt], wfr[ot], acc[mt][ot], 0, 0, 0);
      }
    }

    if (mat == 0) {
#pragma unroll
      for (int ot = 0; ot < 4; ++ot)
#pragma unroll
        for (int nt = 0; nt < 4; ++nt) {
          int f = (nt * 16 + c16) * 256 + w * 64 + ot * 16 + g * 4;
          short4t s;
          s[0] = f2bf(acc[ot][nt][0] * INV_TEMP);
          s[1] = f2bf(acc[ot][nt][1] * INV_TEMP);
          s[2] = f2bf(acc[ot][nt][2] * INV_TEMP);
          s[3] = f2bf(acc[ot][nt][3] * INV_TEMP);
          *(short4t*)&ob[f] = s;
        }
    } else if (mat == 1) {
#pragma unroll
      for (int ot = 0; ot < 4; ++ot)
#pragma unroll
        for (int nt = 0; nt < 4; ++nt) {
          int koo = w * 2 + (ot >> 1);
          int pos = (((ot & 1) * 2 + (g >> 1)) ^ ((c16 >> 1) & 3));
          int f = nt * 4096 + koo * 512 + c16 * 32 + pos * 8 + (g & 1) * 4;
          short4t s;
          s[0] = f2bf(acc[ot][nt][0]);
          s[1] = f2bf(acc[ot][nt][1]);
          s[2] = f2bf(acc[ot][nt][2]);
          s[3] = f2bf(acc[ot][nt][3]);
          *(short4t*)&ob[f] = s;
        }
    } else {  // V: acc[mt][ot], rows m = mt*16+g*4+r, cols o = w*64+ot*16+c16
#pragma unroll
      for (int mt = 0; mt < 4; ++mt)
#pragma unroll
        for (int ot = 0; ot < 4; ++ot) {
          int o = w * 64 + ot * 16 + c16;
          int pos = (mt * 2 + (g >> 1)) ^ (o & 7);
          int f = o * 64 + pos * 8 + (g & 1) * 4;
          short4t s;
          s[0] = f2bf(acc[mt][ot][0]);
          s[1] = f2bf(acc[mt][ot][1]);
          s[2] = f2bf(acc[mt][ot][2]);
          s[3] = f2bf(acc[mt][ot][3]);
          *(short4t*)&ob[f] = s;
        }
    }
    __syncthreads();             // ob assembled (all threads) before blast

    short* dst = (mat == 0) ? qg + ((size_t)b * N_ + n0) * O_
               : (mat == 1) ? kt + (size_t)(b * 256 + (n0 >> 4)) * 4096
                            : vt + (size_t)(b * 64 + (n0 >> 6)) * 16384;
    const uint4* s4p = (const uint4*)ob;
    uint4* d4 = (uint4*)dst;
#pragma unroll
    for (int j = 0; j < 8; ++j) d4[j * 256 + tid] = s4p[j * 256 + tid];

    if (p + 1 < npass) __syncthreads();  // blast done before pass-2 epi WAR
  }
}

// ---------------------------------------------------------------------------
// Flash attention v11 (reverted, proven 99.5us). Grid (16, 32). Block 512.
// 2 WGs/CU. b = x&3; n0 = ((x>>2)*32 + y)*32.
// Waves 0-3 producers (16-key granules, 32 q-rows), 4-7 consumers (64-o).
// Separate role loops with matching barrier counts (66 each) -> register
// overlay. K/V direct global->reg, prefetched one interval ahead.
// LDS: ps 2x(32x72) + lsum = 9.75KB.
// ---------------------------------------------------------------------------
__global__ __launch_bounds__(512, 4) void flash_attn(
    const short* __restrict__ qg, const short* __restrict__ kt,
    const short* __restrict__ vt, float* __restrict__ out) {
  const int xg = blockIdx.x;                       // 0..15
  const int b  = xg & 3;
  const int n0 = (((xg >> 2) << 5) + blockIdx.y) * 32;   // 0..4064 step 32
  const int tid = threadIdx.x;
  const int w = tid >> 6, lane = tid & 63;
  const int g = lane >> 4, c16 = lane & 15;
  const int pw = w & 3;            // producer granule / consumer o-slice

  __shared__ short ps[2][32][72];  // P dbuf: 32 n x 64 m
  __shared__ float lsum[4][32];

  const short* ktb = kt + (size_t)b * N_ * O_;
  const short* vtb = vt + (size_t)b * N_ * O_;

  if (w < 4) {
    // ================= producer: S^T granule pw, exp, ps =================
    bf16x8 qf[2][8];                 // 32 q-rows x 256 o  (64 VGPRs)
    bf16x8 kf[8];                    // K(i) granule        (32 VGPRs)
    float lrun[2] = {0.f, 0.f};
    const int koff = c16 * 32 + ((g ^ ((c16 >> 1) & 3)) * 8);

#pragma unroll
    for (int nt = 0; nt < 2; ++nt) {
      const short* qrow =
          qg + (size_t)(b * N_ + n0 + nt * 16 + c16) * O_ + g * 8;
#pragma unroll
      for (int ko = 0; ko < 8; ++ko)
        qf[nt][ko] = *(const bf16x8*)(qrow + ko * 32);
    }
    {  // K(0)
      const short* kg = ktb + (size_t)pw * 4096;
#pragma unroll
      for (int j = 0; j < 8; ++j)
        kf[j] = *(const bf16x8*)(kg + j * 512 + koff);
    }

    for (int i = 0; i <= NIT; ++i) {
      if (i < NIT) {
        f32x4 sacc[2];
#pragma unroll
        for (int nt = 0; nt < 2; ++nt) sacc[nt] = (f32x4){0.f, 0.f, 0.f, 0.f};
        __builtin_amdgcn_s_setprio(1);
#pragma unroll
        for (int ko = 0; ko < 8; ++ko) {
#pragma unroll
          for (int nt = 0; nt < 2; ++nt)
            sacc[nt] = __builtin_amdgcn_mfma_f32_16x16x32_bf16(
                kf[ko], qf[nt][ko], sacc[nt], 0, 0, 0);
        }
        __builtin_amdgcn_s_setprio(0);
        if (i + 1 < NIT) {  // prefetch K(i+1); lands during next interval
          const short* kg = ktb + (size_t)(4 * (i + 1) + pw) * 4096;
#pragma unroll
          for (int j = 0; j < 8; ++j)
            kf[j] = *(const bf16x8*)(kg + j * 512 + koff);
        }
        // p = exp(s) (no max subtraction: |s| <= ~2.5 by construction)
#pragma unroll
        for (int nt = 0; nt < 2; ++nt) {
          short4t pb;
          float rs = 0.f;
#pragma unroll
          for (int r = 0; r < 4; ++r) {
            float p = __expf(sacc[nt][r]);
            rs += p;
            pb[r] = f2bf(p);
          }
          lrun[nt] += rs;
          *(short4t*)&ps[i & 1][nt * 16 + c16][pw * 16 + g * 4] = pb;
        }
      }
      asm volatile("s_waitcnt lgkmcnt(0)" ::: "memory");
      __builtin_amdgcn_s_barrier();
    }
    // publish granule row-sums
#pragma unroll
    for (int nt = 0; nt < 2; ++nt) {
      float v = lrun[nt];
      v += __shfl_xor(v, 16);
      v += __shfl_xor(v, 32);
      if (lane < 16) lsum[pw][nt * 16 + lane] = v;
    }
    asm volatile("s_waitcnt lgkmcnt(0)" ::: "memory");
    __builtin_amdgcn_s_barrier();                  // barrier #66
  } else {
    // ================= consumer: PV o-slice pw, normalize, store ==========
    bf16x8 vf[8];                    // V(i) slice          (32 VGPRs)
    f32x4 oacc[4][2];                // 64 o x 32 n         (32 VGPRs)
#pragma unroll
    for (int i = 0; i < 4; ++i)
#pragma unroll
      for (int j = 0; j < 2; ++j) oacc[i][j] = (f32x4){0.f, 0.f, 0.f, 0.f};

    for (int i = 0; i <= NIT; ++i) {
      if (i > 0) {  // O += V(i-1) P(i-1)^T  (vf holds V(i-1))
        const int pb_ = (i - 1) & 1;
        __builtin_amdgcn_s_setprio(1);
#pragma unroll
        for (int kk = 0; kk < 2; ++kk) {
          bf16x8 pf[2];
#pragma unroll
          for (int nt = 0; nt < 2; ++nt)
            pf[nt] = *(const bf16x8*)&ps[pb_][nt * 16 + c16][kk * 32 + g * 8];
#pragma unroll
          for (int ot = 0; ot < 4; ++ot) {
#pragma unroll
            for (int nt = 0; nt < 2; ++nt)
              oacc[ot][nt] = __builtin_amdgcn_mfma_f32_16x16x32_bf16(
                  vf[kk * 4 + ot], pf[nt], oacc[ot][nt], 0, 0, 0);
          }
        }
        __builtin_amdgcn_s_setprio(0);
      }
      if (i < NIT) {  // prefetch V(i) for use at interval i+1
        const short* vg = vtb + (size_t)i * 16384;
#pragma unroll
        for (int kk = 0; kk < 2; ++kk)
#pragma unroll
          for (int ot = 0; ot < 4; ++ot)
            vf[kk * 4 + ot] = *(const bf16x8*)(
                vg + (pw * 64 + ot * 16 + c16) * 64 +
                ((kk * 4 + g) ^ (c16 & 7)) * 8);
      }
      asm volatile("s_waitcnt lgkmcnt(0)" ::: "memory");
      __builtin_amdgcn_s_barrier();
    }
    __builtin_amdgcn_s_barrier();                  // barrier #66 (lsum ready)

#pragma unroll
    for (int nt = 0; nt < 2; ++nt) {
      const int nl = nt * 16 + c16;
      float l = lsum[0][nl] + lsum[1][nl] + lsum[2][nl] + lsum[3][nl];
      float li = 1.0f / l;
#pragma unroll
      for (int ot = 0; ot < 4; ++ot) {
        float* op = out + ((size_t)b * O_ + pw * 64 + ot * 16 + g * 4) * N_ +
                    n0 + nl;
#pragma unroll
        for (int r = 0; r < 4; ++r)
          op[(size_t)r * N_] = oacc[ot][nt][r] * li;
      }
    }
  }
}

// ---------------------------------------------------------------------------
extern "C" void kernel_launch(void* const* d_in, const int* in_sizes, int n_in,
                              void* d_out, int out_size, void* d_ws,
                              size_t ws_size, hipStream_t stream) {
  const float* x  = (const float*)d_in[0];
  const float* xx = (const float*)d_in[1];
  const float* Wq = (const float*)d_in[2];
  const float* Wk = (const float*)d_in[3];
  const float* Wv = (const float*)d_in[4];
  float* out = (float*)d_out;

  short* qg = (short*)d_ws;                         // 8.39 MB
  short* kt = qg + (size_t)B_ * N_ * O_;            // 8.39 MB (tiled K)
  short* vt = kt + (size_t)B_ * N_ * O_;            // 8.39 MB (tiled V)
  short* wb = vt + (size_t)B_ * N_ * O_;            // 384 KB

  wcvt<<<768, 256, 0, stream>>>(Wq, Wk, Wv, wb);
  qkv_proj<<<dim3(N_ / 64, B_, 2), 256, 0, stream>>>(x, xx, wb, qg, kt, vt);
  flash_attn<<<dim3(16, 32), 512, 0, stream>>>(qg, kt, vt, out);
}

// Round 11
// 195.500 us; speedup vs baseline: 1.0272x; 1.0272x over previous
//
#include <hip/hip_runtime.h>
#include <hip/hip_bf16.h>

// CrossAttention: B=4, C=256, N=4096, OUT=256, temp=16.
// v19: v12 config (best: 187.0) + L3-prefetch of x/xx inside the wcvt
//      dispatch. v14 warm rows showed proj reads 26MB at ~1.3TB/s: the
//      256B-chunk/16KB-stride transpose read page-thrashes DRAM (each
//      access opens a ~2KB page, uses 256B). MLP/issue fixes (v12/v13/
//      v18) couldn't help - the limiter is DRAM pages. x+xx = 33.6MB
//      fits Infinity Cache (memory-side SRAM, no page penalty): 512
//      extra blocks in wcvt read x/xx contiguously at full HBM BW
//      (~6us) with asm keep-alive (no DCE); proj's strided reads then
//      hit L3. No new dispatch -> no new gap.
//  - proj/flash byte-identical to v12/v11 (flash 97.7us control).
// Workspace: qg 8.4MB + kt 8.4MB + vt 8.4MB + wb 384KB.

typedef __attribute__((ext_vector_type(8))) short bf16x8;
typedef __attribute__((ext_vector_type(4))) float f32x4;
typedef __attribute__((ext_vector_type(4))) short short4t;

constexpr int B_ = 4;
constexpr int C_ = 256;
constexpr int N_ = 4096;
constexpr int O_ = 256;
constexpr float INV_TEMP = 1.0f / 16.0f;
constexpr int NIT = 64;   // 64-key blocks (all 4096 keys, SPLIT=1)

__device__ __forceinline__ short f2bf(float f) {
  union { float f; unsigned u; } v; v.f = f;
  unsigned r = v.u + 0x7fffu + ((v.u >> 16) & 1u);   // RNE
  return (short)(r >> 16);
}

// ---------------------------------------------------------------------------
// wcvt + L3 prefetch. Grid 1280 x 256.
// Blocks 0..767: W f32->bf16 (v12 verbatim).
// Blocks 768..1279: stream x (256 blocks) / xx (256 blocks) through L3 with
// contiguous f32x4 loads; asm keep-alive prevents DCE. 65536B per block.
// ---------------------------------------------------------------------------
__global__ void wcvt(const float* __restrict__ Wq, const float* __restrict__ Wk,
                     const float* __restrict__ Wv, short* __restrict__ wb,
                     const float* __restrict__ x, const float* __restrict__ xx) {
  const int bx = blockIdx.x;
  if (bx < 768) {
    int i = bx * 256 + threadIdx.x;              // 0..196607
    int mat = i >> 16, off = i & 65535;
    const float* W = (mat == 0) ? Wq : (mat == 1 ? Wk : Wv);
    wb[i] = f2bf(W[off]);
  } else {
    const int p = bx - 768;                      // 0..511
    const float* src = (p < 256) ? x : xx;
    const int pb = p & 255;                      // 256 blocks per src
    const f32x4* base =
        (const f32x4*)src + (size_t)pb * 4096 + threadIdx.x;
#pragma unroll
    for (int j = 0; j < 16; ++j) {
      f32x4 v = base[j * 256];                   // 64KB/block, coalesced
      asm volatile("" :: "v"(v[0]), "v"(v[1]), "v"(v[2]), "v"(v[3]));
    }
  }
}

// ---------------------------------------------------------------------------
// Projections (v12 verbatim). Grid (64, B, 3). Block 256 (4 waves).
// ---------------------------------------------------------------------------
__global__ __launch_bounds__(256, 2) void qkv_proj(
    const float* __restrict__ x, const float* __restrict__ xx,
    const short* __restrict__ wb,
    short* __restrict__ qg, short* __restrict__ kt, short* __restrict__ vt) {
  const int n0  = blockIdx.x * 64;
  const int b   = blockIdx.y;
  const int mat = blockIdx.z;
  const float* src = (mat == 0) ? x : xx;
  const short* W   = wb + mat * 65536;
  const int tid = threadIdx.x;
  const int w = tid >> 6, lane = tid & 63;
  const int g = lane >> 4, c16 = lane & 15;

  __shared__ __align__(16) short xs[64][264];   // staged tile / out assembly

  {  // transpose staging, MLP-deep: all 64 strided loads, then write.
    const int n = tid & 63, cq = tid >> 6;
    const float* sp = src + (size_t)b * C_ * N_ + n0 + n;
    float xr[64];                                // stays in VGPRs (static idx)
#pragma unroll
    for (int rep = 0; rep < 16; ++rep)
#pragma unroll
      for (int j = 0; j < 4; ++j)
        xr[rep * 4 + j] = sp[(size_t)(rep * 16 + cq * 4 + j) * N_];
#pragma unroll
    for (int rep = 0; rep < 16; ++rep) {
      int c = rep * 16 + cq * 4;
      short4t s4;
#pragma unroll
      for (int j = 0; j < 4; ++j) s4[j] = f2bf(xr[rep * 4 + j]);
      *(short4t*)&xs[n][c] = s4;
    }
  }
  __syncthreads();

  f32x4 acc[4][4];
#pragma unroll
  for (int i = 0; i < 4; ++i)
#pragma unroll
    for (int j = 0; j < 4; ++j) acc[i][j] = (f32x4){0.f, 0.f, 0.f, 0.f};

#pragma unroll
  for (int ko = 0; ko < 8; ++ko) {
    bf16x8 wfr[4], xfr[4];
#pragma unroll
    for (int ot = 0; ot < 4; ++ot)
      wfr[ot] = *(const bf16x8*)&W[(w * 64 + ot * 16 + c16) * C_ + ko * 32 + g * 8];
#pragma unroll
    for (int nt = 0; nt < 4; ++nt)
      xfr[nt] = *(const bf16x8*)&xs[nt * 16 + c16][ko * 32 + g * 8];
    if (mat < 2) {
#pragma unroll
      for (int ot = 0; ot < 4; ++ot)
#pragma unroll
        for (int nt = 0; nt < 4; ++nt)
          acc[ot][nt] = __builtin_amdgcn_mfma_f32_16x16x32_bf16(
              wfr[ot], xfr[nt], acc[ot][nt], 0, 0, 0);
    } else {  // V: swapped operands -> D rows = m, cols = o
#pragma unroll
      for (int mt = 0; mt < 4; ++mt)
#pragma unroll
        for (int ot = 0; ot < 4; ++ot)
          acc[mt][ot] = __builtin_amdgcn_mfma_f32_16x16x32_bf16(
              xfr[mt], wfr[ot], acc[mt][ot], 0, 0, 0);
    }
  }

  __syncthreads();               // xs tile reads done; reuse as out-assembly
  short* ob = &xs[0][0];         // 16384 shorts used

  if (mat == 0) {
#pragma unroll
    for (int ot = 0; ot < 4; ++ot)
#pragma unroll
      for (int nt = 0; nt < 4; ++nt) {
        int f = (nt * 16 + c16) * 256 + w * 64 + ot * 16 + g * 4;
        short4t s;
        s[0] = f2bf(acc[ot][nt][0] * INV_TEMP);
        s[1] = f2bf(acc[ot][nt][1] * INV_TEMP);
        s[2] = f2bf(acc[ot][nt][2] * INV_TEMP);
        s[3] = f2bf(acc[ot][nt][3] * INV_TEMP);
        *(short4t*)&ob[f] = s;
      }
  } else if (mat == 1) {
#pragma unroll
    for (int ot = 0; ot < 4; ++ot)
#pragma unroll
      for (int nt = 0; nt < 4; ++nt) {
        int koo = w * 2 + (ot >> 1);
        int pos = (((ot & 1) * 2 + (g >> 1)) ^ ((c16 >> 1) & 3));
        int f = nt * 4096 + koo * 512 + c16 * 32 + pos * 8 + (g & 1) * 4;
        short4t s;
        s[0] = f2bf(acc[ot][nt][0]);
        s[1] = f2bf(acc[ot][nt][1]);
        s[2] = f2bf(acc[ot][nt][2]);
        s[3] = f2bf(acc[ot][nt][3]);
        *(short4t*)&ob[f] = s;
      }
  } else {  // V: acc[mt][ot], rows m = mt*16+g*4+r, cols o = w*64+ot*16+c16
#pragma unroll
    for (int mt = 0; mt < 4; ++mt)
#pragma unroll
      for (int ot = 0; ot < 4; ++ot) {
        int o = w * 64 + ot * 16 + c16;
        int pos = (mt * 2 + (g >> 1)) ^ (o & 7);
        int f = o * 64 + pos * 8 + (g & 1) * 4;
        short4t s;
        s[0] = f2bf(acc[mt][ot][0]);
        s[1] = f2bf(acc[mt][ot][1]);
        s[2] = f2bf(acc[mt][ot][2]);
        s[3] = f2bf(acc[mt][ot][3]);
        *(short4t*)&ob[f] = s;
      }
  }
  __syncthreads();

  short* dst = (mat == 0) ? qg + ((size_t)b * N_ + n0) * O_
             : (mat == 1) ? kt + (size_t)(b * 256 + (n0 >> 4)) * 4096
                          : vt + (size_t)(b * 64 + (n0 >> 6)) * 16384;
  const uint4* s4 = (const uint4*)ob;
  uint4* d4 = (uint4*)dst;
#pragma unroll
  for (int j = 0; j < 8; ++j) d4[j * 256 + tid] = s4[j * 256 + tid];
}

// ---------------------------------------------------------------------------
// Flash attention v11 (unchanged, proven 97.7us). Grid (16, 32). Block 512.
// 2 WGs/CU. b = x&3; n0 = ((x>>2)*32 + y)*32.
// Waves 0-3 producers (16-key granules, 32 q-rows), 4-7 consumers (64-o).
// Separate role loops with matching barrier counts (66 each) -> register
// overlay. K/V direct global->reg, prefetched one interval ahead.
// LDS: ps 2x(32x72) + lsum = 9.75KB.
// ---------------------------------------------------------------------------
__global__ __launch_bounds__(512, 4) void flash_attn(
    const short* __restrict__ qg, const short* __restrict__ kt,
    const short* __restrict__ vt, float* __restrict__ out) {
  const int xg = blockIdx.x;                       // 0..15
  const int b  = xg & 3;
  const int n0 = (((xg >> 2) << 5) + blockIdx.y) * 32;   // 0..4064 step 32
  const int tid = threadIdx.x;
  const int w = tid >> 6, lane = tid & 63;
  const int g = lane >> 4, c16 = lane & 15;
  const int pw = w & 3;            // producer granule / consumer o-slice

  __shared__ short ps[2][32][72];  // P dbuf: 32 n x 64 m
  __shared__ float lsum[4][32];

  const short* ktb = kt + (size_t)b * N_ * O_;
  const short* vtb = vt + (size_t)b * N_ * O_;

  if (w < 4) {
    // ================= producer: S^T granule pw, exp, ps =================
    bf16x8 qf[2][8];                 // 32 q-rows x 256 o  (64 VGPRs)
    bf16x8 kf[8];                    // K(i) granule        (32 VGPRs)
    float lrun[2] = {0.f, 0.f};
    const int koff = c16 * 32 + ((g ^ ((c16 >> 1) & 3)) * 8);

#pragma unroll
    for (int nt = 0; nt < 2; ++nt) {
      const short* qrow =
          qg + (size_t)(b * N_ + n0 + nt * 16 + c16) * O_ + g * 8;
#pragma unroll
      for (int ko = 0; ko < 8; ++ko)
        qf[nt][ko] = *(const bf16x8*)(qrow + ko * 32);
    }
    {  // K(0)
      const short* kg = ktb + (size_t)pw * 4096;
#pragma unroll
      for (int j = 0; j < 8; ++j)
        kf[j] = *(const bf16x8*)(kg + j * 512 + koff);
    }

    for (int i = 0; i <= NIT; ++i) {
      if (i < NIT) {
        f32x4 sacc[2];
#pragma unroll
        for (int nt = 0; nt < 2; ++nt) sacc[nt] = (f32x4){0.f, 0.f, 0.f, 0.f};
        __builtin_amdgcn_s_setprio(1);
#pragma unroll
        for (int ko = 0; ko < 8; ++ko) {
#pragma unroll
          for (int nt = 0; nt < 2; ++nt)
            sacc[nt] = __builtin_amdgcn_mfma_f32_16x16x32_bf16(
                kf[ko], qf[nt][ko], sacc[nt], 0, 0, 0);
        }
        __builtin_amdgcn_s_setprio(0);
        if (i + 1 < NIT) {  // prefetch K(i+1); lands during next interval
          const short* kg = ktb + (size_t)(4 * (i + 1) + pw) * 4096;
#pragma unroll
          for (int j = 0; j < 8; ++j)
            kf[j] = *(const bf16x8*)(kg + j * 512 + koff);
        }
        // p = exp(s) (no max subtraction: |s| <= ~2.5 by construction)
#pragma unroll
        for (int nt = 0; nt < 2; ++nt) {
          short4t pb;
          float rs = 0.f;
#pragma unroll
          for (int r = 0; r < 4; ++r) {
            float p = __expf(sacc[nt][r]);
            rs += p;
            pb[r] = f2bf(p);
          }
          lrun[nt] += rs;
          *(short4t*)&ps[i & 1][nt * 16 + c16][pw * 16 + g * 4] = pb;
        }
      }
      asm volatile("s_waitcnt lgkmcnt(0)" ::: "memory");
      __builtin_amdgcn_s_barrier();
    }
    // publish granule row-sums
#pragma unroll
    for (int nt = 0; nt < 2; ++nt) {
      float v = lrun[nt];
      v += __shfl_xor(v, 16);
      v += __shfl_xor(v, 32);
      if (lane < 16) lsum[pw][nt * 16 + lane] = v;
    }
    asm volatile("s_waitcnt lgkmcnt(0)" ::: "memory");
    __builtin_amdgcn_s_barrier();                  // barrier #66
  } else {
    // ================= consumer: PV o-slice pw, normalize, store ==========
    bf16x8 vf[8];                    // V(i) slice          (32 VGPRs)
    f32x4 oacc[4][2];                // 64 o x 32 n         (32 VGPRs)
#pragma unroll
    for (int i = 0; i < 4; ++i)
#pragma unroll
      for (int j = 0; j < 2; ++j) oacc[i][j] = (f32x4){0.f, 0.f, 0.f, 0.f};

    for (int i = 0; i <= NIT; ++i) {
      if (i > 0) {  // O += V(i-1) P(i-1)^T  (vf holds V(i-1))
        const int pb_ = (i - 1) & 1;
        __builtin_amdgcn_s_setprio(1);
#pragma unroll
        for (int kk = 0; kk < 2; ++kk) {
          bf16x8 pf[2];
#pragma unroll
          for (int nt = 0; nt < 2; ++nt)
            pf[nt] = *(const bf16x8*)&ps[pb_][nt * 16 + c16][kk * 32 + g * 8];
#pragma unroll
          for (int ot = 0; ot < 4; ++ot) {
#pragma unroll
            for (int nt = 0; nt < 2; ++nt)
              oacc[ot][nt] = __builtin_amdgcn_mfma_f32_16x16x32_bf16(
                  vf[kk * 4 + ot], pf[nt], oacc[ot][nt], 0, 0, 0);
          }
        }
        __builtin_amdgcn_s_setprio(0);
      }
      if (i < NIT) {  // prefetch V(i) for use at interval i+1
        const short* vg = vtb + (size_t)i * 16384;
#pragma unroll
        for (int kk = 0; kk < 2; ++kk)
#pragma unroll
          for (int ot = 0; ot < 4; ++ot)
            vf[kk * 4 + ot] = *(const bf16x8*)(
                vg + (pw * 64 + ot * 16 + c16) * 64 +
                ((kk * 4 + g) ^ (c16 & 7)) * 8);
      }
      asm volatile("s_waitcnt lgkmcnt(0)" ::: "memory");
      __builtin_amdgcn_s_barrier();
    }
    __builtin_amdgcn_s_barrier();                  // barrier #66 (lsum ready)

#pragma unroll
    for (int nt = 0; nt < 2; ++nt) {
      const int nl = nt * 16 + c16;
      float l = lsum[0][nl] + lsum[1][nl] + lsum[2][nl] + lsum[3][nl];
      float li = 1.0f / l;
#pragma unroll
      for (int ot = 0; ot < 4; ++ot) {
        float* op = out + ((size_t)b * O_ + pw * 64 + ot * 16 + g * 4) * N_ +
                    n0 + nl;
#pragma unroll
        for (int r = 0; r < 4; ++r)
          op[(size_t)r * N_] = oacc[ot][nt][r] * li;
      }
    }
  }
}

// ---------------------------------------------------------------------------
extern "C" void kernel_launch(void* const* d_in, const int* in_sizes, int n_in,
                              void* d_out, int out_size, void* d_ws,
                              size_t ws_size, hipStream_t stream) {
  const float* x  = (const float*)d_in[0];
  const float* xx = (const float*)d_in[1];
  const float* Wq = (const float*)d_in[2];
  const float* Wk = (const float*)d_in[3];
  const float* Wv = (const float*)d_in[4];
  float* out = (float*)d_out;

  short* qg = (short*)d_ws;                         // 8.39 MB
  short* kt = qg + (size_t)B_ * N_ * O_;            // 8.39 MB (tiled K)
  short* vt = kt + (size_t)B_ * N_ * O_;            // 8.39 MB (tiled V)
  short* wb = vt + (size_t)B_ * N_ * O_;            // 384 KB

  wcvt<<<1280, 256, 0, stream>>>(Wq, Wk, Wv, wb, x, xx);
  qkv_proj<<<dim3(N_ / 64, B_, 3), 256, 0, stream>>>(x, xx, wb, qg, kt, vt);
  flash_attn<<<dim3(16, 32), 512, 0, stream>>>(qg, kt, vt, out);
}